// Round 6
// baseline (321.904 us; speedup 1.0000x reference)
//
#include <hip/hip_runtime.h>

#define ALPHA 0.90483741803595957f

// ---------------------------------------------------------------------------
// K0: fold avgpool into conv kernels.
// W1eff[oc][ch][u][v] (4x2x8x8): conv1 5x5 pad2 + pool4  => 8x8 stride-4 conv
// W2eff[oc][ch][u][v] (8x4x4x4): conv2 3x3 pad1 + pool2  => 4x4 stride-2 conv
// ---------------------------------------------------------------------------
__global__ void prep_weights(const float* __restrict__ w1, const float* __restrict__ w2,
                             float* __restrict__ w1e, float* __restrict__ w2e) {
    int idx = blockIdx.x * 256 + threadIdx.x;
    if (idx < 512) {
        int v = idx & 7, u = (idx >> 3) & 7, ch = (idx >> 6) & 1, oc = idx >> 7;
        float s = 0.f;
        for (int a = 0; a < 5; ++a) {
            int i = u - a; if (i < 0 || i > 3) continue;
            for (int b = 0; b < 5; ++b) {
                int j = v - b; if (j < 0 || j > 3) continue;
                s += w1[((oc * 2 + ch) * 5 + a) * 5 + b];
            }
        }
        w1e[idx] = s * (1.f / 16.f);
    } else if (idx < 1024) {
        int k = idx - 512;
        int v = k & 3, u = (k >> 2) & 3, ch = (k >> 4) & 3, oc = k >> 6;
        float s = 0.f;
        for (int a = 0; a < 3; ++a) {
            int i = u - a; if (i < 0 || i > 1) continue;
            for (int b = 0; b < 3; ++b) {
                int j = v - b; if (j < 0 || j > 1) continue;
                s += w2[((oc * 4 + ch) * 3 + a) * 3 + b];
            }
        }
        w2e[k] = s * 0.25f;
    }
}

// ---------------------------------------------------------------------------
// Zero the padded spike buffer (borders must be 0; ws is poisoned each call).
// spk[b][t][4][10][12] = 6,144,000 floats = 1,536,000 float4.
// ---------------------------------------------------------------------------
__global__ __launch_bounds__(256) void zero_spk(float4* __restrict__ p) {
    p[blockIdx.x * 256 + threadIdx.x] = make_float4(0.f, 0.f, 0.f, 0.f);
}

// ---------------------------------------------------------------------------
// K1 v4: conv1 + pool4 (8x8/stride-4 effective kernel).
// 2 images per 256-thread block -> 23 KB LDS -> 6 blocks/CU = 24 waves/CU.
// Weights in LDS, layout [ch][r][oc][8] -> wave-uniform ds_read broadcasts.
// Tile rows padded to 40 floats -> b128 reads at the bank floor.
// ---------------------------------------------------------------------------
__global__ __launch_bounds__(256) void conv1_pool(const float* __restrict__ x,
                                                  const float* __restrict__ w1e,
                                                  float* __restrict__ y1) {
    __shared__ __align__(16) float tile[2][2][36][40];  // 23040 B
    __shared__ __align__(16) float wlds[512];           // [ch][r][oc][8]
    int tid = threadIdx.x;

    float4* t4 = (float4*)&tile[0][0][0][0];
    #pragma unroll
    for (int k = 0; k < 6; ++k) {
        int i = tid + k * 256;
        if (i < 1440) t4[i] = make_float4(0.f, 0.f, 0.f, 0.f);
    }
    for (int j = tid; j < 512; j += 256) {
        int oc = j >> 7, ch = (j >> 6) & 1, r = (j >> 3) & 7, c = j & 7;
        wlds[((ch * 8 + r) * 4 + oc) * 8 + c] = w1e[j];
    }
    __syncthreads();

    int w = tid >> 6, lane = tid & 63;
    int im = w >> 1, half = w & 1;
    long gi = (long)blockIdx.x * 2 + im;                // bt < 12800
    const float* src = x + gi * 2048 + half * 1024;     // ch = half
    #pragma unroll
    for (int k = 0; k < 4; ++k) {
        int e = k * 256 + lane * 4;                     // 0..1023, 16B aligned
        float4 d = *(const float4*)(src + e);
        int r = e >> 5, c = e & 31;
        float* dst = &tile[im][half][r + 2][c + 2];     // 8B aligned
        *(float2*)dst = make_float2(d.x, d.y);
        *(float2*)(dst + 2) = make_float2(d.z, d.w);
    }
    __syncthreads();

    int ocp = w & 1;                                    // oc pair 2*ocp, 2*ocp+1
    int p = lane >> 3, q = lane & 7;
    float acc0 = 0.f, acc1 = 0.f;
    #pragma unroll
    for (int ch = 0; ch < 2; ++ch) {
        #pragma unroll
        for (int r = 0; r < 8; ++r) {
            const float* row = &tile[im][ch][4 * p + r][4 * q];   // 16B aligned
            float4 a = *(const float4*)row;
            float4 b = *(const float4*)(row + 4);
            const float* wr = &wlds[((ch * 8 + r) * 4 + ocp * 2) * 8];  // uniform
            float4 wa = *(const float4*)(wr + 0), wb = *(const float4*)(wr + 4);
            acc0 += wa.x * a.x + wa.y * a.y + wa.z * a.z + wa.w * a.w
                  + wb.x * b.x + wb.y * b.y + wb.z * b.z + wb.w * b.w;
            wa = *(const float4*)(wr + 8); wb = *(const float4*)(wr + 12);
            acc1 += wa.x * a.x + wa.y * a.y + wa.z * a.z + wa.w * a.w
                  + wb.x * b.x + wb.y * b.y + wb.z * b.z + wb.w * b.w;
        }
    }
    float* dst = y1 + gi * 256 + ocp * 128 + lane;      // f = oc*64 + p*8 + q
    dst[0] = acc0; dst[64] = acc1;
}

// ---------------------------------------------------------------------------
// K2: stage-1 exp_leak + LIF. 32768 independent chains (b,f), no barriers,
// 4-deep prefetch. Writes spikes into PADDED spk[b][t][4][10][12] interior
// cell [ch][r+1][c+1] (borders pre-zeroed by zero_spk).
// ---------------------------------------------------------------------------
__global__ __launch_bounds__(256) void scan1(const float* __restrict__ y1,
                                             float* __restrict__ spk) {
    int idx = blockIdx.x * 256 + threadIdx.x;   // 128 b * 256 f
    int b = idx >> 8, f = idx & 255;
    int ch = f >> 6, r = (f >> 3) & 7, c = f & 7;
    const float* p = y1 + (long)b * 25600 + f;
    float* o = spk + (long)b * 48000 + ch * 120 + (r + 1) * 12 + (c + 1);
    float v1 = 0.f, v2 = 0.f;
    float c0 = p[0], c1 = p[256], c2 = p[512], c3 = p[768];
    for (int t = 0; t < 100; t += 4) {
        float n0 = 0.f, n1 = 0.f, n2 = 0.f, n3 = 0.f;
        if (t < 96) {
            const float* pp = p + (t + 4) * 256;
            n0 = pp[0]; n1 = pp[256]; n2 = pp[512]; n3 = pp[768];
        }
        v1 = ALPHA * v1 + c0; v2 = ALPHA * v2 + v1;
        float s = (v2 >= 1.f) ? 1.f : 0.f; v2 -= s; o[t * 480] = s;
        v1 = ALPHA * v1 + c1; v2 = ALPHA * v2 + v1;
        s = (v2 >= 1.f) ? 1.f : 0.f; v2 -= s; o[(t + 1) * 480] = s;
        v1 = ALPHA * v1 + c2; v2 = ALPHA * v2 + v1;
        s = (v2 >= 1.f) ? 1.f : 0.f; v2 -= s; o[(t + 2) * 480] = s;
        v1 = ALPHA * v1 + c3; v2 = ALPHA * v2 + v1;
        s = (v2 >= 1.f) ? 1.f : 0.f; v2 -= s; o[(t + 3) * 480] = s;
        c0 = n0; c1 = n1; c2 = n2; c3 = n3;
    }
}

// ---------------------------------------------------------------------------
// K3: conv2+pool2 + stage-2 LIF. One thread per (b, oc, p, q); blocks of 64,
// blockIdx = b*2 + half. No barriers/LDS: padded spike tiles (480 floats/t)
// read from L1/L2, indexing identical to the verified LDS version.
// Weights = 16 named float4 SSA values (VGPR-resident). s2[b][t][128].
// ---------------------------------------------------------------------------
__global__ __launch_bounds__(64, 1) void scan2(const float* __restrict__ spk,
                                               const float* __restrict__ w2e,
                                               float* __restrict__ s2) {
    int b = blockIdx.x >> 1, h = blockIdx.x & 1;
    int g = h * 64 + threadIdx.x;                 // 0..127
    int oc = g >> 4, p = (g >> 2) & 3, q = g & 3;

    const float4* wp = (const float4*)(w2e + oc * 64);
    float4 w00 = wp[0],  w01 = wp[1],  w02 = wp[2],  w03 = wp[3];
    float4 w04 = wp[4],  w05 = wp[5],  w06 = wp[6],  w07 = wp[7];
    float4 w08 = wp[8],  w09 = wp[9],  w10 = wp[10], w11 = wp[11];
    float4 w12 = wp[12], w13 = wp[13], w14 = wp[14], w15 = wp[15];

    const float* sp = spk + (long)b * 48000;
    float* os = s2 + (long)b * 12800 + g;
    float v2a = 0.f, v2b = 0.f;

#define C2(cc, rr, W, P) { const float* rowp = st + (cc) * 120 + (2 * p + (rr)) * 12 + 2 * q; \
        float2 a_ = *(const float2*)rowp; float2 b_ = *(const float2*)(rowp + 2);             \
        P += W.x * a_.x + W.y * a_.y + W.z * b_.x + W.w * b_.y; }

    #pragma unroll 2
    for (int t = 0; t < 100; ++t) {
        const float* st = sp + t * 480;
        float p0 = 0.f, p1 = 0.f, p2 = 0.f, p3 = 0.f;
        C2(0, 0, w00, p0) C2(0, 1, w01, p0) C2(0, 2, w02, p0) C2(0, 3, w03, p0)
        C2(1, 0, w04, p1) C2(1, 1, w05, p1) C2(1, 2, w06, p1) C2(1, 3, w07, p1)
        C2(2, 0, w08, p2) C2(2, 1, w09, p2) C2(2, 2, w10, p2) C2(2, 3, w11, p2)
        C2(3, 0, w12, p3) C2(3, 1, w13, p3) C2(3, 2, w14, p3) C2(3, 3, w15, p3)
        float acc = (p0 + p1) + (p2 + p3);
        v2a = ALPHA * v2a + acc; v2b = ALPHA * v2b + v2a;
        float ss = (v2b >= 1.f) ? 1.f : 0.f; v2b -= ss;
        os[t * 128] = ss;
    }
#undef C2
}

// ---------------------------------------------------------------------------
// K4: out[bt][o] = sum_f s2[bt][f] * lw[o][f].  One wave per bt.
// ---------------------------------------------------------------------------
__global__ __launch_bounds__(256) void linear_out(const float* __restrict__ s2,
                                                  const float* __restrict__ lw,
                                                  float* __restrict__ out) {
    int tid = threadIdx.x;
    long bt = (long)blockIdx.x * 4 + (tid >> 6);
    int lane = tid & 63;
    float2 v = *(const float2*)(s2 + bt * 128 + lane * 2);
    float w00 = lw[lane * 2], w01 = lw[lane * 2 + 1];
    float w10 = lw[128 + lane * 2], w11 = lw[128 + lane * 2 + 1];
    float a0 = v.x * w00 + v.y * w01;
    float a1 = v.x * w10 + v.y * w11;
    #pragma unroll
    for (int off = 32; off; off >>= 1) {
        a0 += __shfl_down(a0, off);
        a1 += __shfl_down(a1, off);
    }
    if (lane == 0) { out[bt * 2] = a0; out[bt * 2 + 1] = a1; }
}

extern "C" void kernel_launch(void* const* d_in, const int* in_sizes, int n_in,
                              void* d_out, int out_size, void* d_ws, size_t ws_size,
                              hipStream_t stream) {
    const float* x  = (const float*)d_in[0];   // [128,100,2,32,32]
    const float* w1 = (const float*)d_in[1];   // [4,2,5,5]
    const float* w2 = (const float*)d_in[2];   // [8,4,3,3]
    const float* lw = (const float*)d_in[3];   // [2,128]
    float* out = (float*)d_out;                // [128,100,2]

    float* ws  = (float*)d_ws;
    float* w1e = ws;                  // 512 floats
    float* w2e = ws + 512;            // 512 floats
    float* y1  = ws + 1024;           // 12800*256 = 3,276,800 floats
    float* spk = y1 + 3276800;        // padded spikes: 128*100*480 = 6,144,000
    float* s2  = spk + 6144000;       // 12800*128 = 1,638,400 floats

    prep_weights<<<4, 256, 0, stream>>>(w1, w2, w1e, w2e);
    zero_spk<<<6000, 256, 0, stream>>>((float4*)spk);
    conv1_pool<<<6400, 256, 0, stream>>>(x, w1e, y1);
    scan1<<<128, 256, 0, stream>>>(y1, spk);
    scan2<<<256, 64, 0, stream>>>(spk, w2e, s2);
    linear_out<<<3200, 256, 0, stream>>>(s2, lw, out);
}